// Round 1
// baseline (131.406 us; speedup 1.0000x reference)
//
#include <hip/hip_runtime.h>

#define CCH 256
#define HH  256
#define WW  256
#define HWSZ (HH * WW)
#define NROI 512
#define RBIN 7
#define NBIN (RBIN * RBIN)                    // 49
#define NTASK (2 * NBIN)                      // 98 (bin, point-pair) tasks
#define TFEAT_BYTES ((size_t)HWSZ * CCH * 2)  // 32 MiB bf16 HWC

typedef float vfloat4 __attribute__((ext_vector_type(4)));

__device__ __forceinline__ unsigned short f2bf_rne(float f) {
    unsigned u = __float_as_uint(f);
    u = (u + 0x7fffu + ((u >> 16) & 1u)) >> 16;
    return (unsigned short)u;
}

// ---------------- Kernel 1: (C,H,W) fp32 -> (H,W,C) bf16 transpose ----------
// R11: XOR-swizzled LDS, conflict-free in BOTH passes (unchanged — near its
// 96 MiB streaming bound).
__global__ __launch_bounds__(256)
void transpose_chw_to_hwc_bf16(const float* __restrict__ feat,
                               unsigned short* __restrict__ tfeat)
{
    __shared__ __align__(16) float tile[64 * 64];  // 16 KB, swizzled
    const int t   = threadIdx.x;              // 0..255
    const int hw0 = blockIdx.x * 64;
    const int c0  = blockIdx.y * 64;

    const int cl_r = t >> 4;                  // 0..15 (+j*16)
    const int fc   = t & 15;                  // float4 column 0..15

    vfloat4 v[4];
    #pragma unroll
    for (int j = 0; j < 4; ++j) {
        v[j] = __builtin_nontemporal_load(
            (const vfloat4*)(feat + (size_t)(c0 + cl_r + j * 16) * HWSZ + hw0 + 4 * fc));
    }
    #pragma unroll
    for (int j = 0; j < 4; ++j) {
        const int cl = cl_r + j * 16;
        const int p  = (4 * fc) ^ (4 * ((cl >> 2) & 7));
        *(vfloat4*)&tile[cl * 64 + p] = v[j];          // ds_write_b128
    }
    __syncthreads();

    const int cl_w = (t & 15) * 4;            // 0,4,..,60
    const int swz  = 4 * ((t & 15) & 7);      // == 4*(((cl_w+i)>>2)&7) for i<4
    #pragma unroll
    for (int j = 0; j < 4; ++j) {
        const int hl = (t >> 4) + j * 16;     // 0..63 over passes
        const int pc = hl ^ swz;
        ushort4 w;
        w.x = f2bf_rne(tile[(cl_w + 0) * 64 + pc]);
        w.y = f2bf_rne(tile[(cl_w + 1) * 64 + pc]);
        w.z = f2bf_rne(tile[(cl_w + 2) * 64 + pc]);
        w.w = f2bf_rne(tile[(cl_w + 3) * 64 + pc]);
        // 16 lanes (same hl) cover 64 consecutive channels -> 128 B segment
        *(ushort4*)(tfeat + (size_t)(hw0 + hl) * CCH + c0 + cl_w) = w;
    }
}

// ---------------- Kernel 2: fused sample + pool + broadcast ----------------
// R12 restructure:
//  * __launch_bounds__(1024, 8): force 2 blocks/CU (32 waves/CU), VGPR<=64.
//    Previous version could legally sit at 65..128 VGPR -> 1 block/CU ->
//    50% occupancy on a gather-latency-bound kernel.
//  * Task = (bin, point-pair): 98 tasks over 16 waves -> critical wave 7
//    tasks vs 6.125 avg (1.14x) instead of 4 bins vs 3.06 (1.31x). Also
//    kills the acc[8] array + i-loop -> much lower register pressure, more
//    independent loads in flight per iteration.
//  * Broadcast store vectorized to dwordx4 (3136 stores vs 12544).
__global__ __launch_bounds__(1024, 8)
void roialign_fused(const unsigned short* __restrict__ tfeat,
                    const float* __restrict__ rois,
                    float* __restrict__ out)
{
    const int n    = blockIdx.x;
    const int t    = threadIdx.x;
    const int wave = t >> 6;                  // 0..15
    const int lane = t & 63;
    const int half = lane >> 5;               // point selector within pair
    const int cOff = (lane & 31) * 8;         // 8 channels per lane

    __shared__ float tmax[NTASK];             // per (bin, pair) max
    __shared__ float pooled[NBIN];

    const float y0 = rois[n * 4 + 0];
    const float x0 = rois[n * 4 + 1];
    const float sh = (rois[n * 4 + 2] - y0) * (1.0f / (float)RBIN);
    const float sw = (rois[n * 4 + 3] - x0) * (1.0f / (float)RBIN);

    for (int task = wave; task < NTASK; task += 16) {
        const int bin = task >> 1;
        const int i   = task & 1;             // which point-pair (sy row)
        const int by  = bin / RBIN;
        const int bx  = bin - by * RBIN;

        const int point = i * 2 + half;       // 0..3
        const int sy = point >> 1;
        const int sx = point & 1;

        const float y = y0 + sh * (float)by +
                        ((sy == 0) ? (sh * (1.0f / 3.0f)) : (sh * (2.0f / 3.0f)));
        const float x = x0 + sw * (float)bx +
                        ((sx == 0) ? (sw * (1.0f / 3.0f)) : (sw * (2.0f / 3.0f)));

        int iy1 = (int)floorf(y);
        int iy2 = iy1 + 1;
        int ix1 = (int)floorf(x);
        int ix2 = ix1 + 1;
        iy1 = min(max(iy1, 0), HH - 1);
        iy2 = min(max(iy2, 0), HH - 1);
        ix1 = min(max(ix1, 0), WW - 1);
        ix2 = min(max(ix2, 0), WW - 1);

        // weights from clipped indices (matches reference, incl. edge strip)
        const float wy1 = y - (float)iy1;
        const float wy2 = (float)iy2 - y;
        const float wx1 = x - (float)ix1;
        const float wx2 = (float)ix2 - x;

        const uint4 A = *(const uint4*)(tfeat + (size_t)(iy1 * WW + ix1) * CCH + cOff);
        const uint4 B = *(const uint4*)(tfeat + (size_t)(iy1 * WW + ix2) * CCH + cOff);
        const uint4 C = *(const uint4*)(tfeat + (size_t)(iy2 * WW + ix1) * CCH + cOff);
        const uint4 D = *(const uint4*)(tfeat + (size_t)(iy2 * WW + ix2) * CCH + cOff);
        const unsigned* ap = (const unsigned*)&A;
        const unsigned* bp = (const unsigned*)&B;
        const unsigned* cp = (const unsigned*)&C;
        const unsigned* dp = (const unsigned*)&D;

        float m = -INFINITY;
        #pragma unroll
        for (int k = 0; k < 4; ++k) {
            const unsigned ua = ap[k], ub = bp[k], uc = cp[k], ud = dp[k];
            {
                const float f11 = __uint_as_float(ua << 16);
                const float f12 = __uint_as_float(ub << 16);
                const float f21 = __uint_as_float(uc << 16);
                const float f22 = __uint_as_float(ud << 16);
                const float p = f11 * wx2 + f12 * wx1;
                const float q = f21 * wx2 + f22 * wx1;
                m = fmaxf(m, p * wy2 + q * wy1);
            }
            {
                const float f11 = __uint_as_float(ua & 0xffff0000u);
                const float f12 = __uint_as_float(ub & 0xffff0000u);
                const float f21 = __uint_as_float(uc & 0xffff0000u);
                const float f22 = __uint_as_float(ud & 0xffff0000u);
                const float p = f11 * wx2 + f12 * wx1;
                const float q = f21 * wx2 + f22 * wx1;
                m = fmaxf(m, p * wy2 + q * wy1);
            }
        }

        // 64-lane butterfly: max over both points of the pair x 256 ch
        #pragma unroll
        for (int off = 32; off > 0; off >>= 1)
            m = fmaxf(m, __shfl_xor(m, off, 64));

        if (lane == 0) tmax[task] = m;
    }
    __syncthreads();

    if (t < NBIN) pooled[t] = fmaxf(tmax[2 * t], tmax[2 * t + 1]);
    __syncthreads();

    // broadcast (C x 49) as dwordx4: 3136 float4 per roi, 16B aligned
    float* o = out + (size_t)n * (CCH * NBIN);
    #pragma unroll
    for (int k = 0; k < 4; ++k) {
        const int idx4 = t + k * 1024;
        if (idx4 < (CCH * NBIN) / 4) {
            int r = (idx4 * 4) % NBIN;
            vfloat4 v;
            v.x = pooled[r]; r = (r == NBIN - 1) ? 0 : r + 1;
            v.y = pooled[r]; r = (r == NBIN - 1) ? 0 : r + 1;
            v.z = pooled[r]; r = (r == NBIN - 1) ? 0 : r + 1;
            v.w = pooled[r];
            __builtin_nontemporal_store(v, (vfloat4*)o + idx4);
        }
    }
}

// ---------------- Fallback (round-1 direct kernel, used if ws too small) ----
__global__ __launch_bounds__(256)
void roialign_direct_kernel(const float* __restrict__ feat,
                            const float* __restrict__ rois,
                            float* __restrict__ out)
{
    const int n = blockIdx.x;
    const int t = threadIdx.x;
    __shared__ float ptmax[196];
    __shared__ float pooled[NBIN];

    const float y0  = rois[n * 4 + 0];
    const float x0  = rois[n * 4 + 1];
    const float sh  = (rois[n * 4 + 2] - y0) / (float)RBIN;
    const float sw  = (rois[n * 4 + 3] - x0) / (float)RBIN;

    const bool active = (t < 196);
    int off11 = 0, off12 = 0, off21 = 0, off22 = 0;
    float wx1 = 0.f, wx2 = 0.f, wy1 = 0.f, wy2 = 0.f;
    if (active) {
        const int py = t / 14, px = t % 14;
        const int by = py >> 1, sy = py & 1;
        const int bx = px >> 1, sx = px & 1;
        const float y = y0 + sh * (float)by + ((sy == 0) ? (sh / 3.0f) : (2.0f * sh / 3.0f));
        const float x = x0 + sw * (float)bx + ((sx == 0) ? (sw / 3.0f) : (2.0f * sw / 3.0f));
        int iy1 = (int)floorf(y), iy2 = iy1 + 1;
        int ix1 = (int)floorf(x), ix2 = ix1 + 1;
        iy1 = min(max(iy1, 0), HH - 1); iy2 = min(max(iy2, 0), HH - 1);
        ix1 = min(max(ix1, 0), WW - 1); ix2 = min(max(ix2, 0), WW - 1);
        wy1 = y - (float)iy1; wy2 = (float)iy2 - y;
        wx1 = x - (float)ix1; wx2 = (float)ix2 - x;
        off11 = iy1 * WW + ix1; off12 = iy1 * WW + ix2;
        off21 = iy2 * WW + ix1; off22 = iy2 * WW + ix2;
    }
    if (active) {
        float m = -INFINITY;
        const float* f = feat;
        #pragma unroll 4
        for (int c = 0; c < CCH; ++c) {
            const float p = f[off11] * wx2 + f[off12] * wx1;
            const float q = f[off21] * wx2 + f[off22] * wx1;
            m = fmaxf(m, p * wy2 + q * wy1);
            f += HWSZ;
        }
        ptmax[t] = m;
    }
    __syncthreads();
    if (t < NBIN) {
        const int by = t / RBIN, bx = t % RBIN;
        const int p00 = (2 * by) * 14 + 2 * bx;
        pooled[t] = fmaxf(fmaxf(ptmax[p00], ptmax[p00 + 1]),
                          fmaxf(ptmax[p00 + 14], ptmax[p00 + 15]));
    }
    __syncthreads();
    float* o = out + (size_t)n * (CCH * NBIN);
    for (int idx = t; idx < CCH * NBIN; idx += 256)
        o[idx] = pooled[idx % NBIN];
}

extern "C" void kernel_launch(void* const* d_in, const int* in_sizes, int n_in,
                              void* d_out, int out_size, void* d_ws, size_t ws_size,
                              hipStream_t stream)
{
    const float* feat = (const float*)d_in[0];   // (256,256,256) fp32
    const float* rois = (const float*)d_in[1];   // (512,4) fp32
    float* out = (float*)d_out;                  // (512,256,7,7) fp32

    if (ws_size < TFEAT_BYTES) {
        roialign_direct_kernel<<<NROI, 256, 0, stream>>>(feat, rois, out);
        return;
    }

    unsigned short* tfeat = (unsigned short*)d_ws;

    dim3 tgrid(HWSZ / 64, CCH / 64);
    transpose_chw_to_hwc_bf16<<<tgrid, 256, 0, stream>>>(feat, tfeat);

    roialign_fused<<<NROI, 1024, 0, stream>>>(tfeat, rois, out);
}

// Round 2
// 130.885 us; speedup vs baseline: 1.0040x; 1.0040x over previous
//
#include <hip/hip_runtime.h>

#define CCH 256
#define HH  256
#define WW  256
#define HWSZ (HH * WW)
#define NROI 512
#define RBIN 7
#define NBIN (RBIN * RBIN)                    // 49
#define NTASK (2 * NBIN)                      // 98 (bin, point-pair) tasks
#define TFEAT_BYTES ((size_t)HWSZ * CCH * 2)  // 32 MiB bf16 HWC

typedef float vfloat4 __attribute__((ext_vector_type(4)));

__device__ __forceinline__ unsigned short f2bf_rne(float f) {
    unsigned u = __float_as_uint(f);
    u = (u + 0x7fffu + ((u >> 16) & 1u)) >> 16;
    return (unsigned short)u;
}

// ---------------- Kernel 1: (C,H,W) fp32 -> (H,W,C) bf16 transpose ----------
// XOR-swizzled LDS, conflict-free in BOTH passes (unchanged — near its
// 96 MiB streaming bound).
__global__ __launch_bounds__(256)
void transpose_chw_to_hwc_bf16(const float* __restrict__ feat,
                               unsigned short* __restrict__ tfeat)
{
    __shared__ __align__(16) float tile[64 * 64];  // 16 KB, swizzled
    const int t   = threadIdx.x;              // 0..255
    const int hw0 = blockIdx.x * 64;
    const int c0  = blockIdx.y * 64;

    const int cl_r = t >> 4;                  // 0..15 (+j*16)
    const int fc   = t & 15;                  // float4 column 0..15

    vfloat4 v[4];
    #pragma unroll
    for (int j = 0; j < 4; ++j) {
        v[j] = __builtin_nontemporal_load(
            (const vfloat4*)(feat + (size_t)(c0 + cl_r + j * 16) * HWSZ + hw0 + 4 * fc));
    }
    #pragma unroll
    for (int j = 0; j < 4; ++j) {
        const int cl = cl_r + j * 16;
        const int p  = (4 * fc) ^ (4 * ((cl >> 2) & 7));
        *(vfloat4*)&tile[cl * 64 + p] = v[j];          // ds_write_b128
    }
    __syncthreads();

    const int cl_w = (t & 15) * 4;            // 0,4,..,60
    const int swz  = 4 * ((t & 15) & 7);      // == 4*(((cl_w+i)>>2)&7) for i<4
    #pragma unroll
    for (int j = 0; j < 4; ++j) {
        const int hl = (t >> 4) + j * 16;     // 0..63 over passes
        const int pc = hl ^ swz;
        ushort4 w;
        w.x = f2bf_rne(tile[(cl_w + 0) * 64 + pc]);
        w.y = f2bf_rne(tile[(cl_w + 1) * 64 + pc]);
        w.z = f2bf_rne(tile[(cl_w + 2) * 64 + pc]);
        w.w = f2bf_rne(tile[(cl_w + 3) * 64 + pc]);
        // 16 lanes (same hl) cover 64 consecutive channels -> 128 B segment
        *(ushort4*)(tfeat + (size_t)(hw0 + hl) * CCH + c0 + cl_w) = w;
    }
}

// ---------------- Kernel 2: fused sample + pool + broadcast ----------------
// R13: no in-loop cross-lane reduction.
//  Phase 1: per task, each lane keeps the max over its 8 channels (x 2
//    points folded per half-wave) IN REGISTER and writes ONE float to LDS.
//    The task loop is pure {addr calc -> 4 independent dwordx4 -> FMA
//    chain -> ds_write}: no serial shfl ladder, so the compiler can
//    overlap task k+1's gathers with task k's FMA tail.
//  Phase 2: one barrier, then 98x64 -> 49 reduced in parallel: 16 thr/bin,
//    32 B contiguous LDS reads, 7 fmax, 4-step width-16 butterfly.
//  Replaces ~588 serial shfl+fmax per block with a ~200-cycle epilogue.
__global__ __launch_bounds__(1024, 8)
void roialign_fused(const unsigned short* __restrict__ tfeat,
                    const float* __restrict__ rois,
                    float* __restrict__ out)
{
    const int n    = blockIdx.x;
    const int t    = threadIdx.x;
    const int wave = t >> 6;                  // 0..15
    const int lane = t & 63;
    const int half = lane >> 5;               // point selector within pair
    const int cOff = (lane & 31) * 8;         // 8 channels per lane

    __shared__ __align__(16) float tmax[NTASK * 64];  // 25088 B per-lane partials
    __shared__ float pooled[NBIN];

    const float y0 = rois[n * 4 + 0];
    const float x0 = rois[n * 4 + 1];
    const float sh = (rois[n * 4 + 2] - y0) * (1.0f / (float)RBIN);
    const float sw = (rois[n * 4 + 3] - x0) * (1.0f / (float)RBIN);

    #pragma unroll 2
    for (int task = wave; task < NTASK; task += 16) {
        const int bin = task >> 1;
        const int i   = task & 1;             // which point-pair (sy row)
        const int by  = bin / RBIN;
        const int bx  = bin - by * RBIN;

        const int point = i * 2 + half;       // 0..3
        const int sy = point >> 1;
        const int sx = point & 1;

        const float y = y0 + sh * (float)by +
                        ((sy == 0) ? (sh * (1.0f / 3.0f)) : (sh * (2.0f / 3.0f)));
        const float x = x0 + sw * (float)bx +
                        ((sx == 0) ? (sw * (1.0f / 3.0f)) : (sw * (2.0f / 3.0f)));

        int iy1 = (int)floorf(y);
        int iy2 = iy1 + 1;
        int ix1 = (int)floorf(x);
        int ix2 = ix1 + 1;
        iy1 = min(max(iy1, 0), HH - 1);
        iy2 = min(max(iy2, 0), HH - 1);
        ix1 = min(max(ix1, 0), WW - 1);
        ix2 = min(max(ix2, 0), WW - 1);

        // weights from clipped indices (matches reference, incl. edge strip)
        const float wy1 = y - (float)iy1;
        const float wy2 = (float)iy2 - y;
        const float wx1 = x - (float)ix1;
        const float wx2 = (float)ix2 - x;

        const uint4 A = *(const uint4*)(tfeat + (size_t)(iy1 * WW + ix1) * CCH + cOff);
        const uint4 B = *(const uint4*)(tfeat + (size_t)(iy1 * WW + ix2) * CCH + cOff);
        const uint4 C = *(const uint4*)(tfeat + (size_t)(iy2 * WW + ix1) * CCH + cOff);
        const uint4 D = *(const uint4*)(tfeat + (size_t)(iy2 * WW + ix2) * CCH + cOff);
        const unsigned* ap = (const unsigned*)&A;
        const unsigned* bp = (const unsigned*)&B;
        const unsigned* cp = (const unsigned*)&C;
        const unsigned* dp = (const unsigned*)&D;

        float m = -INFINITY;
        #pragma unroll
        for (int k = 0; k < 4; ++k) {
            const unsigned ua = ap[k], ub = bp[k], uc = cp[k], ud = dp[k];
            {
                const float f11 = __uint_as_float(ua << 16);
                const float f12 = __uint_as_float(ub << 16);
                const float f21 = __uint_as_float(uc << 16);
                const float f22 = __uint_as_float(ud << 16);
                const float p = f11 * wx2 + f12 * wx1;
                const float q = f21 * wx2 + f22 * wx1;
                m = fmaxf(m, p * wy2 + q * wy1);
            }
            {
                const float f11 = __uint_as_float(ua & 0xffff0000u);
                const float f12 = __uint_as_float(ub & 0xffff0000u);
                const float f21 = __uint_as_float(uc & 0xffff0000u);
                const float f22 = __uint_as_float(ud & 0xffff0000u);
                const float p = f11 * wx2 + f12 * wx1;
                const float q = f21 * wx2 + f22 * wx1;
                m = fmaxf(m, p * wy2 + q * wy1);
            }
        }

        tmax[task * 64 + lane] = m;           // one ds_write, no conflicts
    }
    __syncthreads();

    // Phase 2: 16 threads per bin reduce 128 partials (2 tasks x 64 lanes).
    if (t < NBIN * 16) {
        const int b = t >> 4;                 // bin
        const int j = t & 15;
        const float* src = &tmax[b * 128 + j * 8];
        const vfloat4 a = *(const vfloat4*)(src);
        const vfloat4 c = *(const vfloat4*)(src + 4);
        float m = fmaxf(fmaxf(fmaxf(a.x, a.y), fmaxf(a.z, a.w)),
                        fmaxf(fmaxf(c.x, c.y), fmaxf(c.z, c.w)));
        #pragma unroll
        for (int off = 8; off > 0; off >>= 1)
            m = fmaxf(m, __shfl_xor(m, off, 16));
        if (j == 0) pooled[b] = m;
    }
    __syncthreads();

    // broadcast (C x 49) as dwordx4: 3136 float4 per roi, 16B aligned
    float* o = out + (size_t)n * (CCH * NBIN);
    #pragma unroll
    for (int k = 0; k < 4; ++k) {
        const int idx4 = t + k * 1024;
        if (idx4 < (CCH * NBIN) / 4) {
            int r = (idx4 * 4) % NBIN;
            vfloat4 v;
            v.x = pooled[r]; r = (r == NBIN - 1) ? 0 : r + 1;
            v.y = pooled[r]; r = (r == NBIN - 1) ? 0 : r + 1;
            v.z = pooled[r]; r = (r == NBIN - 1) ? 0 : r + 1;
            v.w = pooled[r];
            __builtin_nontemporal_store(v, (vfloat4*)o + idx4);
        }
    }
}

// ---------------- Fallback (round-1 direct kernel, used if ws too small) ----
__global__ __launch_bounds__(256)
void roialign_direct_kernel(const float* __restrict__ feat,
                            const float* __restrict__ rois,
                            float* __restrict__ out)
{
    const int n = blockIdx.x;
    const int t = threadIdx.x;
    __shared__ float ptmax[196];
    __shared__ float pooled[NBIN];

    const float y0  = rois[n * 4 + 0];
    const float x0  = rois[n * 4 + 1];
    const float sh  = (rois[n * 4 + 2] - y0) / (float)RBIN;
    const float sw  = (rois[n * 4 + 3] - x0) / (float)RBIN;

    const bool active = (t < 196);
    int off11 = 0, off12 = 0, off21 = 0, off22 = 0;
    float wx1 = 0.f, wx2 = 0.f, wy1 = 0.f, wy2 = 0.f;
    if (active) {
        const int py = t / 14, px = t % 14;
        const int by = py >> 1, sy = py & 1;
        const int bx = px >> 1, sx = px & 1;
        const float y = y0 + sh * (float)by + ((sy == 0) ? (sh / 3.0f) : (2.0f * sh / 3.0f));
        const float x = x0 + sw * (float)bx + ((sx == 0) ? (sw / 3.0f) : (2.0f * sw / 3.0f));
        int iy1 = (int)floorf(y), iy2 = iy1 + 1;
        int ix1 = (int)floorf(x), ix2 = ix1 + 1;
        iy1 = min(max(iy1, 0), HH - 1); iy2 = min(max(iy2, 0), HH - 1);
        ix1 = min(max(ix1, 0), WW - 1); ix2 = min(max(ix2, 0), WW - 1);
        wy1 = y - (float)iy1; wy2 = (float)iy2 - y;
        wx1 = x - (float)ix1; wx2 = (float)ix2 - x;
        off11 = iy1 * WW + ix1; off12 = iy1 * WW + ix2;
        off21 = iy2 * WW + ix1; off22 = iy2 * WW + ix2;
    }
    if (active) {
        float m = -INFINITY;
        const float* f = feat;
        #pragma unroll 4
        for (int c = 0; c < CCH; ++c) {
            const float p = f[off11] * wx2 + f[off12] * wx1;
            const float q = f[off21] * wx2 + f[off22] * wx1;
            m = fmaxf(m, p * wy2 + q * wy1);
            f += HWSZ;
        }
        ptmax[t] = m;
    }
    __syncthreads();
    if (t < NBIN) {
        const int by = t / RBIN, bx = t % RBIN;
        const int p00 = (2 * by) * 14 + 2 * bx;
        pooled[t] = fmaxf(fmaxf(ptmax[p00], ptmax[p00 + 1]),
                          fmaxf(ptmax[p00 + 14], ptmax[p00 + 15]));
    }
    __syncthreads();
    float* o = out + (size_t)n * (CCH * NBIN);
    for (int idx = t; idx < CCH * NBIN; idx += 256)
        o[idx] = pooled[idx % NBIN];
}

extern "C" void kernel_launch(void* const* d_in, const int* in_sizes, int n_in,
                              void* d_out, int out_size, void* d_ws, size_t ws_size,
                              hipStream_t stream)
{
    const float* feat = (const float*)d_in[0];   // (256,256,256) fp32
    const float* rois = (const float*)d_in[1];   // (512,4) fp32
    float* out = (float*)d_out;                  // (512,256,7,7) fp32

    if (ws_size < TFEAT_BYTES) {
        roialign_direct_kernel<<<NROI, 256, 0, stream>>>(feat, rois, out);
        return;
    }

    unsigned short* tfeat = (unsigned short*)d_ws;

    dim3 tgrid(HWSZ / 64, CCH / 64);
    transpose_chw_to_hwc_bf16<<<tgrid, 256, 0, stream>>>(feat, tfeat);

    roialign_fused<<<NROI, 1024, 0, stream>>>(tfeat, rois, out);
}